// Round 12
// baseline (1339.235 us; speedup 1.0000x reference)
//
#include <hip/hip_runtime.h>
#include <math.h>

#define N_NODES 20000
#define N_EDGES 320000
#define EP (N_EDGES + N_NODES)   // with self loops
#define HEADS 5

__device__ __forceinline__ float lrelu(float s) { return (s > 0.f) ? s : 0.2f * s; }

// fp32 -> bf16 bits, round-to-nearest-even
__device__ __forceinline__ unsigned f2bf(float f) {
  unsigned u = __float_as_uint(f);
  return (u + 0x7fffu + ((u >> 16) & 1u)) >> 16;
}

// ---------------- CSR build ----------------
__global__ void count_deg_k(const int* __restrict__ ei, int* __restrict__ deg) {
  int e = blockIdx.x * blockDim.x + threadIdx.x;
  if (e >= EP) return;
  int dst = (e < N_EDGES) ? ei[N_EDGES + e] : (e - N_EDGES);
  atomicAdd(&deg[dst], 1);
}

__global__ __launch_bounds__(256) void scan1_k(const int* __restrict__ deg,
                                               int* __restrict__ offs,
                                               int* __restrict__ bsum) {
  __shared__ int buf[256];
  int tid = threadIdx.x, i = blockIdx.x * 256 + tid;
  int v = (i < N_NODES) ? deg[i] : 0;
  buf[tid] = v;
  __syncthreads();
  for (int o = 1; o < 256; o <<= 1) {
    int t = (tid >= o) ? buf[tid - o] : 0;
    __syncthreads();
    buf[tid] += t;
    __syncthreads();
  }
  if (i < N_NODES) offs[i] = buf[tid] - v;   // block-local exclusive
  if (tid == 255) bsum[blockIdx.x] = buf[255];
}

__global__ __launch_bounds__(128) void scan2_k(int* __restrict__ bsum, int nb) {
  __shared__ int buf[128];
  int tid = threadIdx.x;
  int v = (tid < nb) ? bsum[tid] : 0;
  buf[tid] = v;
  __syncthreads();
  for (int o = 1; o < 128; o <<= 1) {
    int t = (tid >= o) ? buf[tid - o] : 0;
    __syncthreads();
    buf[tid] += t;
    __syncthreads();
  }
  if (tid < nb) bsum[tid] = buf[tid] - v;    // exclusive
}

__global__ void scan3_k(int* __restrict__ offs, const int* __restrict__ bsum) {
  int i = blockIdx.x * 256 + threadIdx.x;
  if (i < N_NODES) offs[i] += bsum[blockIdx.x];
  if (i == 0) offs[N_NODES] = EP;
}

__global__ void scatter_k(const int* __restrict__ ei, const int* __restrict__ offs,
                          int* __restrict__ cursor, int* __restrict__ ssrc) {
  int e = blockIdx.x * blockDim.x + threadIdx.x;
  if (e >= EP) return;
  int src, dst;
  if (e < N_EDGES) { src = ei[e]; dst = ei[N_EDGES + e]; }
  else             { src = e - N_EDGES; dst = src; }
  int pos = atomicAdd(&cursor[dst], 1);
  ssrc[offs[dst] + pos] = src;
}

// ---------------- pack [W2 | W3] into Wc[64][320] ----------------
__global__ void pack23_k(const float* __restrict__ W2, const float* __restrict__ W3,
                         float* __restrict__ Wc) {
  int t = blockIdx.x * blockDim.x + threadIdx.x;   // 64*160
  if (t >= 64 * 160) return;
  int k = t / 160, j = t % 160;
  Wc[k * 320 + j]       = W2[t];
  Wc[k * 320 + 160 + j] = W3[t];
}

// ---------------- fp32 tiled GEMM + fused att-sums; C stored as BF16 slices ----------------
// C[M,N] = A[M,K] @ B[K,N]; BM=BN=64, BK=16, 256 threads, 4x4/thread.
// LDS stride 68 (conflict-free), single buffer, register prefetch.
// __launch_bounds__(256, 8): cap VGPR at 64 — R11's epilogue bloated the
// allocator to 92 VGPR, collapsing occupancy 41%->17% (the R8 lesson again).
// True live demand in the K-loop is ~50; any spill lands in the cold epilogue.
// C written bf16 (RNE) in 64-col slices: Cb[((bn/64)*M + r)*64 + (c-bn)].
template <int CH>
__global__ __launch_bounds__(256, 8) void sgemm_fused_k(
    const float* __restrict__ A, const float* __restrict__ B,
    unsigned short* __restrict__ Cb,
    const float* __restrict__ attAs, const float* __restrict__ attAd,
    const float* __restrict__ attBs, const float* __restrict__ attBd,
    float* __restrict__ as_out, float* __restrict__ ad_out,
    int M, int N, int K) {
  __shared__ float As[16][68];
  __shared__ float Bs[16][68];
  int bm = blockIdx.x * 64, bn = blockIdx.y * 64;
  int tid = threadIdx.x;
  int tr = (tid / 16) * 4;
  int tc = (tid % 16) * 4;
  float acc[4][4] = {};

  int arow = tid >> 2, ac4 = (tid & 3) << 2;     // A tile: 64 rows x 4 float4
  int brow = tid >> 4, bc4 = (tid & 15) << 2;    // B tile: 16 rows x 16 float4

  int nit = K >> 4;
  const float4 zero4 = make_float4(0.f, 0.f, 0.f, 0.f);

  float4 pa = (bm + arow < M) ? *(const float4*)&A[(size_t)(bm + arow) * K + ac4] : zero4;
  float4 pb = *(const float4*)&B[(size_t)brow * N + bn + bc4];
  As[ac4 + 0][arow] = pa.x; As[ac4 + 1][arow] = pa.y;
  As[ac4 + 2][arow] = pa.z; As[ac4 + 3][arow] = pa.w;
  *(float4*)&Bs[brow][bc4] = pb;
  __syncthreads();

  for (int it = 0; it < nit; ++it) {
    bool more = (it + 1 < nit);
    if (more) {
      int k0 = (it + 1) << 4;
      pa = (bm + arow < M) ? *(const float4*)&A[(size_t)(bm + arow) * K + k0 + ac4] : zero4;
      pb = *(const float4*)&B[(size_t)(k0 + brow) * N + bn + bc4];
    }
#pragma unroll
    for (int k = 0; k < 16; k++) {
      float av[4], bv[4];
#pragma unroll
      for (int j = 0; j < 4; j++) { av[j] = As[k][tr + j]; bv[j] = Bs[k][tc + j]; }
#pragma unroll
      for (int i = 0; i < 4; i++)
#pragma unroll
        for (int j = 0; j < 4; j++) acc[i][j] += av[i] * bv[j];
    }
    if (more) {
      __syncthreads();
      As[ac4 + 0][arow] = pa.x; As[ac4 + 1][arow] = pa.y;
      As[ac4 + 2][arow] = pa.z; As[ac4 + 3][arow] = pa.w;
      *(float4*)&Bs[brow][bc4] = pb;
      __syncthreads();
    }
  }

  int gs = bn >> 6;
#pragma unroll
  for (int i = 0; i < 4; i++) {
    int r = bm + tr + i;
    if (r < M) {
      unsigned p0 = f2bf(acc[i][0]) | (f2bf(acc[i][1]) << 16);
      unsigned p1 = f2bf(acc[i][2]) | (f2bf(acc[i][3]) << 16);
      *(uint2*)&Cb[((size_t)gs * M + r) * 64 + tc] = make_uint2(p0, p1);
    }
  }

  // fused attention sums (fp32 accumulator — exact)
  int u  = (bn + tc) / CH;
  int cc = tc % CH;
  const float* avs; const float* avd;
  if (CH == 64)       { avs = attAs + u * 64 + cc;           avd = attAd + u * 64 + cc; }
  else if (u < HEADS) { avs = attAs + u * 32 + cc;           avd = attAd + u * 32 + cc; }
  else                { avs = attBs + (u - HEADS) * 32 + cc; avd = attBd + (u - HEADS) * 32 + cc; }
  float w_s[4], w_d[4];
#pragma unroll
  for (int j = 0; j < 4; j++) { w_s[j] = avs[j]; w_d[j] = avd[j]; }
#pragma unroll
  for (int i = 0; i < 4; i++) {
    float ps = acc[i][0] * w_s[0] + acc[i][1] * w_s[1] + acc[i][2] * w_s[2] + acc[i][3] * w_s[3];
    float pd = acc[i][0] * w_d[0] + acc[i][1] * w_d[1] + acc[i][2] * w_d[2] + acc[i][3] * w_d[3];
#pragma unroll
    for (int o = 1; o < CH / 4; o <<= 1) {
      ps += __shfl_xor(ps, o);
      pd += __shfl_xor(pd, o);
    }
    int r = bm + tr + i;
    if (((tid & ((CH / 4) - 1)) == 0) && r < M) {
      as_out[(size_t)u * M + r] = ps;
      ad_out[(size_t)u * M + r] = pd;
    }
  }
}

// bf16-quad load helper: uint2 -> 4 floats
__device__ __forceinline__ void bf4(uint2 v, float& f0, float& f1, float& f2, float& f3) {
  f0 = __uint_as_float(v.x << 16);
  f1 = __uint_as_float(v.x & 0xffff0000u);
  f2 = __uint_as_float(v.y << 16);
  f3 = __uint_as_float(v.y & 0xffff0000u);
}

// ---------------- layer 1: block per node, 5 waves (wave = head), LDS reduce ----------------
// Gather reads bf16 xw rows (128 B/row, 16 lanes x uint2), 16 edges in flight,
// fully convergent tail. __shfl executed by ALL lanes (inactive-source
// ds_bpermute is undefined on CDNA — the R3-R5 bug).
__global__ __launch_bounds__(320) void agg1_k(const int* __restrict__ offs,
                                              const int* __restrict__ ssrc,
                                              const float* __restrict__ a_s,
                                              const float* __restrict__ a_d,
                                              const uint2* __restrict__ xwb,
                                              const float* __restrict__ b1,
                                              float* __restrict__ h1) {
  int n = blockIdx.x;
  int u = threadIdx.x >> 6;          // wave = head/unit
  int lane = threadIdx.x & 63;
  int off = offs[n], end = offs[n + 1];
  int deg = end - off;
  float ad = a_d[(size_t)u * N_NODES + n];
  const float* asl = a_s + (size_t)u * N_NODES;
  const uint2* xb  = xwb + (size_t)u * N_NODES * 16;   // slice u, 16 uint2/row
  int g = lane >> 4, q = lane & 15;
  float ax = 0.f, ay = 0.f, az = 0.f, aw = 0.f;

  if (deg <= 64) {
    int s = 0;
    float e = -1e30f;
    if (lane < deg) { s = ssrc[off + lane]; e = lrelu(asl[s] + ad); }
    float m = e;
#pragma unroll
    for (int o = 32; o > 0; o >>= 1) m = fmaxf(m, __shfl_xor(m, o));
    float p = (lane < deg) ? __expf(e - m) : 0.f;
    float den = p;
#pragma unroll
    for (int o = 32; o > 0; o >>= 1) den += __shfl_xor(den, o);
    float alpha = p * (1.f / (den + 1e-16f));

    for (int base = 0; base < deg; base += 16) {
      float alv[4];
      uint2 v[4];
#pragma unroll
      for (int t = 0; t < 4; t++) {
        int ee = base + t * 4 + g;
        bool ok = ee < deg;
        int es = ok ? ee : 0;                 // lane 0 always valid (self-loop)
        float alr = __shfl(alpha, es);        // all 64 lanes execute
        int   sv  = __shfl(s, es);
        alv[t] = ok ? alr : 0.f;
        v[t] = xb[(size_t)sv * 16 + q];       // unconditional
      }
#pragma unroll
      for (int t = 0; t < 4; t++) {
        float f0, f1, f2, f3;
        bf4(v[t], f0, f1, f2, f3);
        ax += alv[t] * f0; ay += alv[t] * f1;
        az += alv[t] * f2; aw += alv[t] * f3;
      }
    }
  } else {
    float m = -1e30f;
    for (int i = off + lane; i < end; i += 64) m = fmaxf(m, lrelu(asl[ssrc[i]] + ad));
#pragma unroll
    for (int o = 32; o > 0; o >>= 1) m = fmaxf(m, __shfl_xor(m, o));
    float den = 0.f;
    for (int i = off + lane; i < end; i += 64) den += __expf(lrelu(asl[ssrc[i]] + ad) - m);
#pragma unroll
    for (int o = 32; o > 0; o >>= 1) den += __shfl_xor(den, o);
    float inv = 1.f / (den + 1e-16f);
    for (int base = off; base < end; base += 4) {
      int e = base + g;
      if (e < end) {
        int sv = ssrc[e];
        float al = __expf(lrelu(asl[sv] + ad) - m) * inv;
        float f0, f1, f2, f3;
        bf4(xb[(size_t)sv * 16 + q], f0, f1, f2, f3);
        ax += al * f0; ay += al * f1; az += al * f2; aw += al * f3;
      }
    }
  }

#pragma unroll
  for (int o = 16; o < 64; o <<= 1) {
    ax += __shfl_xor(ax, o); ay += __shfl_xor(ay, o);
    az += __shfl_xor(az, o); aw += __shfl_xor(aw, o);
  }

  __shared__ float sacc[HEADS][64];
  if (g == 0) *(float4*)&sacc[u][q * 4] = make_float4(ax, ay, az, aw);
  __syncthreads();
  if (threadIdx.x < 64) {
    int t = threadIdx.x;
    float v = sacc[0][t] + sacc[1][t] + sacc[2][t] + sacc[3][t] + sacc[4][t];
    v = v * 0.2f + b1[t];
    h1[(size_t)n * 64 + t] = fmaxf(v, 0.f);
  }
}

// ---------------- layers 2+3: block per node, 5 waves (wave = pair 2g,2g+1) ----------------
__global__ __launch_bounds__(320) void agg23_k(const int* __restrict__ offs,
                                               const int* __restrict__ ssrc,
                                               const float* __restrict__ a_s,
                                               const float* __restrict__ a_d,
                                               const uint2* __restrict__ xwb,
                                               const float* __restrict__ b2,
                                               const float* __restrict__ b3,
                                               float* __restrict__ z_out,
                                               float* __restrict__ mu_out,
                                               float* __restrict__ lv_out) {
  int n = blockIdx.x;
  int gp = threadIdx.x >> 6;         // wave = pair index
  int lane = threadIdx.x & 63;
  int ulo = 2 * gp, uhi = 2 * gp + 1;
  int off = offs[n], end = offs[n + 1];
  int deg = end - off;
  float adlo = a_d[(size_t)ulo * N_NODES + n];
  float adhi = a_d[(size_t)uhi * N_NODES + n];
  const float* aslo = a_s + (size_t)ulo * N_NODES;
  const float* ashi = a_s + (size_t)uhi * N_NODES;
  const uint2* xb   = xwb + (size_t)gp * N_NODES * 16;
  int g = lane >> 4, q = lane & 15;
  float ax = 0.f, ay = 0.f, az = 0.f, aw = 0.f;

  if (deg <= 64) {
    int s = 0;
    float elo = -1e30f, ehi = -1e30f;
    if (lane < deg) {
      s = ssrc[off + lane];
      elo = lrelu(aslo[s] + adlo);
      ehi = lrelu(ashi[s] + adhi);
    }
    float mlo = elo, mhi = ehi;
#pragma unroll
    for (int o = 32; o > 0; o >>= 1) {
      mlo = fmaxf(mlo, __shfl_xor(mlo, o));
      mhi = fmaxf(mhi, __shfl_xor(mhi, o));
    }
    float plo = (lane < deg) ? __expf(elo - mlo) : 0.f;
    float phi = (lane < deg) ? __expf(ehi - mhi) : 0.f;
    float dlo = plo, dhi = phi;
#pragma unroll
    for (int o = 32; o > 0; o >>= 1) {
      dlo += __shfl_xor(dlo, o);
      dhi += __shfl_xor(dhi, o);
    }
    float allo = plo * (1.f / (dlo + 1e-16f));
    float alhi = phi * (1.f / (dhi + 1e-16f));

    for (int base = 0; base < deg; base += 16) {
      float alv[4];
      uint2 v[4];
#pragma unroll
      for (int t = 0; t < 4; t++) {
        int ee = base + t * 4 + g;
        bool ok = ee < deg;
        int es = ok ? ee : 0;                 // lane 0 always valid
        float a1 = __shfl(allo, es);          // all 64 lanes execute
        float a2 = __shfl(alhi, es);
        int   sv = __shfl(s, es);
        float alr = (q < 8) ? a1 : a2;
        alv[t] = ok ? alr : 0.f;
        v[t] = xb[(size_t)sv * 16 + q];       // unconditional
      }
#pragma unroll
      for (int t = 0; t < 4; t++) {
        float f0, f1, f2, f3;
        bf4(v[t], f0, f1, f2, f3);
        ax += alv[t] * f0; ay += alv[t] * f1;
        az += alv[t] * f2; aw += alv[t] * f3;
      }
    }
  } else {
    float mlo = -1e30f, mhi = -1e30f;
    for (int i = off + lane; i < end; i += 64) {
      int sv = ssrc[i];
      mlo = fmaxf(mlo, lrelu(aslo[sv] + adlo));
      mhi = fmaxf(mhi, lrelu(ashi[sv] + adhi));
    }
#pragma unroll
    for (int o = 32; o > 0; o >>= 1) {
      mlo = fmaxf(mlo, __shfl_xor(mlo, o));
      mhi = fmaxf(mhi, __shfl_xor(mhi, o));
    }
    float dlo = 0.f, dhi = 0.f;
    for (int i = off + lane; i < end; i += 64) {
      int sv = ssrc[i];
      dlo += __expf(lrelu(aslo[sv] + adlo) - mlo);
      dhi += __expf(lrelu(ashi[sv] + adhi) - mhi);
    }
#pragma unroll
    for (int o = 32; o > 0; o >>= 1) {
      dlo += __shfl_xor(dlo, o);
      dhi += __shfl_xor(dhi, o);
    }
    float ilo = 1.f / (dlo + 1e-16f), ihi = 1.f / (dhi + 1e-16f);
    for (int base = off; base < end; base += 4) {
      int e = base + g;
      if (e < end) {
        int sv = ssrc[e];
        float al;
        if (q < 8) al = __expf(lrelu(aslo[sv] + adlo) - mlo) * ilo;
        else       al = __expf(lrelu(ashi[sv] + adhi) - mhi) * ihi;
        float f0, f1, f2, f3;
        bf4(xb[(size_t)sv * 16 + q], f0, f1, f2, f3);
        ax += al * f0; ay += al * f1; az += al * f2; aw += al * f3;
      }
    }
  }

#pragma unroll
  for (int o = 16; o < 64; o <<= 1) {
    ax += __shfl_xor(ax, o); ay += __shfl_xor(ay, o);
    az += __shfl_xor(az, o); aw += __shfl_xor(aw, o);
  }

  __shared__ float sacc[HEADS][2][32];
  if (g == 0)
    *(float4*)&sacc[gp][q >> 3][(q & 7) * 4] = make_float4(ax, ay, az, aw);
  __syncthreads();
  if (threadIdx.x < 64) {
    int t = threadIdx.x;
    if (t < 32) {
      float v = sacc[0][0][t] + sacc[0][1][t] + sacc[1][0][t] + sacc[1][1][t] + sacc[2][0][t];
      v = v * 0.2f + b2[t];
      z_out[(size_t)n * 32 + t]  = v;
      mu_out[(size_t)n * 32 + t] = v;
    } else {
      int c = t - 32;
      float v = sacc[2][1][c] + sacc[3][0][c] + sacc[3][1][c] + sacc[4][0][c] + sacc[4][1][c];
      v = v * 0.2f + b3[c];
      lv_out[(size_t)n * 32 + c] = v;
    }
  }
}

// ---------------- launch ----------------
extern "C" void kernel_launch(void* const* d_in, const int* in_sizes, int n_in,
                              void* d_out, int out_size, void* d_ws, size_t ws_size,
                              hipStream_t stream) {
  const float* x        = (const float*)d_in[0];
  const int*   ei       = (const int*)d_in[1];
  const float* W1       = (const float*)d_in[2];
  const float* att_src1 = (const float*)d_in[3];
  const float* att_dst1 = (const float*)d_in[4];
  const float* b1       = (const float*)d_in[5];
  const float* W2       = (const float*)d_in[6];
  const float* att_src2 = (const float*)d_in[7];
  const float* att_dst2 = (const float*)d_in[8];
  const float* b2       = (const float*)d_in[9];
  const float* W3       = (const float*)d_in[10];
  const float* att_src3 = (const float*)d_in[11];
  const float* att_dst3 = (const float*)d_in[12];
  const float* b3       = (const float*)d_in[13];
  float* out = (float*)d_out;

  char* w = (char*)d_ws;
  auto alloc = [&](size_t bytes) -> void* {
    void* p = (void*)w;
    w += (bytes + 255) & ~(size_t)255;
    return p;
  };
  int*            deg    = (int*)alloc((size_t)N_NODES * 4);
  int*            offs   = (int*)alloc((size_t)(N_NODES + 1) * 4);
  int*            cursor = (int*)alloc((size_t)N_NODES * 4);
  int*            bsum   = (int*)alloc((size_t)128 * 4);
  int*            ssrc   = (int*)alloc((size_t)EP * 4);
  unsigned short* xwb    = (unsigned short*)alloc((size_t)N_NODES * 320 * 2);  // 12.8 MB bf16
  float*          a_s    = (float*)alloc((size_t)N_NODES * 10 * 4);
  float*          a_d    = (float*)alloc((size_t)N_NODES * 10 * 4);
  float*          h1     = (float*)alloc((size_t)N_NODES * 64 * 4);            // 5.12 MB
  float*          Wc     = (float*)alloc((size_t)64 * 320 * 4);
  // total ~21 MB

  hipMemsetAsync(deg, 0, (size_t)N_NODES * 4, stream);
  hipMemsetAsync(cursor, 0, (size_t)N_NODES * 4, stream);

  int eb = (EP + 255) / 256;
  int nb = (N_NODES + 255) / 256;   // 79
  count_deg_k<<<eb, 256, 0, stream>>>(ei, deg);
  scan1_k<<<nb, 256, 0, stream>>>(deg, offs, bsum);
  scan2_k<<<1, 128, 0, stream>>>(bsum, nb);
  scan3_k<<<nb, 256, 0, stream>>>(offs, bsum);
  scatter_k<<<eb, 256, 0, stream>>>(ei, offs, cursor, ssrc);
  pack23_k<<<40, 256, 0, stream>>>(W2, W3, Wc);

  dim3 gg(313, 5);

  // ---- layer 1 ----
  sgemm_fused_k<64><<<gg, 256, 0, stream>>>(x, W1, xwb, att_src1, att_dst1,
                                            nullptr, nullptr, a_s, a_d,
                                            N_NODES, 320, 256);
  agg1_k<<<N_NODES, 320, 0, stream>>>(offs, ssrc, a_s, a_d, (const uint2*)xwb, b1, h1);

  // ---- layers 2+3 fused ----
  sgemm_fused_k<32><<<gg, 256, 0, stream>>>(h1, Wc, xwb, att_src2, att_dst2,
                                            att_src3, att_dst3, a_s, a_d,
                                            N_NODES, 320, 64);
  agg23_k<<<N_NODES, 320, 0, stream>>>(offs, ssrc, a_s, a_d, (const uint2*)xwb, b2, b3,
                                       out, out + (size_t)N_NODES * 32,
                                       out + (size_t)2 * N_NODES * 32);
}

// Round 13
// 265.178 us; speedup vs baseline: 5.0503x; 5.0503x over previous
//
#include <hip/hip_runtime.h>
#include <math.h>

#define N_NODES 20000
#define N_EDGES 320000
#define EP (N_EDGES + N_NODES)   // with self loops
#define HEADS 5

__device__ __forceinline__ float lrelu(float s) { return (s > 0.f) ? s : 0.2f * s; }

// fp32 -> bf16 bits, round-to-nearest-even
__device__ __forceinline__ unsigned f2bf(float f) {
  unsigned u = __float_as_uint(f);
  return (u + 0x7fffu + ((u >> 16) & 1u)) >> 16;
}

// ---------------- CSR build ----------------
__global__ void count_deg_k(const int* __restrict__ ei, int* __restrict__ deg) {
  int e = blockIdx.x * blockDim.x + threadIdx.x;
  if (e >= EP) return;
  int dst = (e < N_EDGES) ? ei[N_EDGES + e] : (e - N_EDGES);
  atomicAdd(&deg[dst], 1);
}

__global__ __launch_bounds__(256) void scan1_k(const int* __restrict__ deg,
                                               int* __restrict__ offs,
                                               int* __restrict__ bsum) {
  __shared__ int buf[256];
  int tid = threadIdx.x, i = blockIdx.x * 256 + tid;
  int v = (i < N_NODES) ? deg[i] : 0;
  buf[tid] = v;
  __syncthreads();
  for (int o = 1; o < 256; o <<= 1) {
    int t = (tid >= o) ? buf[tid - o] : 0;
    __syncthreads();
    buf[tid] += t;
    __syncthreads();
  }
  if (i < N_NODES) offs[i] = buf[tid] - v;   // block-local exclusive
  if (tid == 255) bsum[blockIdx.x] = buf[255];
}

__global__ __launch_bounds__(128) void scan2_k(int* __restrict__ bsum, int nb) {
  __shared__ int buf[128];
  int tid = threadIdx.x;
  int v = (tid < nb) ? bsum[tid] : 0;
  buf[tid] = v;
  __syncthreads();
  for (int o = 1; o < 128; o <<= 1) {
    int t = (tid >= o) ? buf[tid - o] : 0;
    __syncthreads();
    buf[tid] += t;
    __syncthreads();
  }
  if (tid < nb) bsum[tid] = buf[tid] - v;    // exclusive
}

__global__ void scan3_k(int* __restrict__ offs, const int* __restrict__ bsum) {
  int i = blockIdx.x * 256 + threadIdx.x;
  if (i < N_NODES) offs[i] += bsum[blockIdx.x];
  if (i == 0) offs[N_NODES] = EP;
}

__global__ void scatter_k(const int* __restrict__ ei, const int* __restrict__ offs,
                          int* __restrict__ cursor, int* __restrict__ ssrc) {
  int e = blockIdx.x * blockDim.x + threadIdx.x;
  if (e >= EP) return;
  int src, dst;
  if (e < N_EDGES) { src = ei[e]; dst = ei[N_EDGES + e]; }
  else             { src = e - N_EDGES; dst = src; }
  int pos = atomicAdd(&cursor[dst], 1);
  ssrc[offs[dst] + pos] = src;
}

// ---------------- pack [W2 | W3] into Wc[64][320] ----------------
__global__ void pack23_k(const float* __restrict__ W2, const float* __restrict__ W3,
                         float* __restrict__ Wc) {
  int t = blockIdx.x * blockDim.x + threadIdx.x;   // 64*160
  if (t >= 64 * 160) return;
  int k = t / 160, j = t % 160;
  Wc[k * 320 + j]       = W2[t];
  Wc[k * 320 + 160 + j] = W3[t];
}

// ---------------- fp32 -> bf16 convert (slice layout preserved) ----------------
__global__ __launch_bounds__(256) void conv_bf16_k(const float4* __restrict__ src,
                                                   uint2* __restrict__ dst, int n4) {
  int t = blockIdx.x * blockDim.x + threadIdx.x;
  if (t >= n4) return;
  float4 v = src[t];
  unsigned p0 = f2bf(v.x) | (f2bf(v.y) << 16);
  unsigned p1 = f2bf(v.z) | (f2bf(v.w) << 16);
  dst[t] = make_uint2(p0, p1);
}

// ---------------- fp32 tiled GEMM + fused att-sums epilogue ----------------
// C[M,N] = A[M,K] @ B[K,N]; BM=BN=64, BK=16, 256 threads, 4x4/thread.
// LDS stride 68 (conflict-free), single buffer, register prefetch.
// BF16 template arg selects the C-store type; NO launch-bounds cap (R12 lesson:
// a forced cap spilled the K-loop; R8: dbuf bloat killed occupancy).
// C written in 64-col slices: C[((bn/64)*M + r)*64 + (c-bn)].
template <int CH, bool BF16>
__global__ __launch_bounds__(256) void sgemm_fused_k(
    const float* __restrict__ A, const float* __restrict__ B,
    float* __restrict__ Cf, unsigned short* __restrict__ Cb,
    const float* __restrict__ attAs, const float* __restrict__ attAd,
    const float* __restrict__ attBs, const float* __restrict__ attBd,
    float* __restrict__ as_out, float* __restrict__ ad_out,
    int M, int N, int K) {
  __shared__ float As[16][68];
  __shared__ float Bs[16][68];
  int bm = blockIdx.x * 64, bn = blockIdx.y * 64;
  int tid = threadIdx.x;
  int tr = (tid / 16) * 4;
  int tc = (tid % 16) * 4;
  float acc[4][4] = {};

  int arow = tid >> 2, ac4 = (tid & 3) << 2;     // A tile: 64 rows x 4 float4
  int brow = tid >> 4, bc4 = (tid & 15) << 2;    // B tile: 16 rows x 16 float4

  int nit = K >> 4;
  const float4 zero4 = make_float4(0.f, 0.f, 0.f, 0.f);

  float4 pa = (bm + arow < M) ? *(const float4*)&A[(size_t)(bm + arow) * K + ac4] : zero4;
  float4 pb = *(const float4*)&B[(size_t)brow * N + bn + bc4];
  As[ac4 + 0][arow] = pa.x; As[ac4 + 1][arow] = pa.y;
  As[ac4 + 2][arow] = pa.z; As[ac4 + 3][arow] = pa.w;
  *(float4*)&Bs[brow][bc4] = pb;
  __syncthreads();

  for (int it = 0; it < nit; ++it) {
    bool more = (it + 1 < nit);
    if (more) {
      int k0 = (it + 1) << 4;
      pa = (bm + arow < M) ? *(const float4*)&A[(size_t)(bm + arow) * K + k0 + ac4] : zero4;
      pb = *(const float4*)&B[(size_t)(k0 + brow) * N + bn + bc4];
    }
#pragma unroll
    for (int k = 0; k < 16; k++) {
      float av[4], bv[4];
#pragma unroll
      for (int j = 0; j < 4; j++) { av[j] = As[k][tr + j]; bv[j] = Bs[k][tc + j]; }
#pragma unroll
      for (int i = 0; i < 4; i++)
#pragma unroll
        for (int j = 0; j < 4; j++) acc[i][j] += av[i] * bv[j];
    }
    if (more) {
      __syncthreads();
      As[ac4 + 0][arow] = pa.x; As[ac4 + 1][arow] = pa.y;
      As[ac4 + 2][arow] = pa.z; As[ac4 + 3][arow] = pa.w;
      *(float4*)&Bs[brow][bc4] = pb;
      __syncthreads();
    }
  }

  int gs = bn >> 6;
#pragma unroll
  for (int i = 0; i < 4; i++) {
    int r = bm + tr + i;
    if (r < M) {
      if constexpr (BF16) {
        unsigned p0 = f2bf(acc[i][0]) | (f2bf(acc[i][1]) << 16);
        unsigned p1 = f2bf(acc[i][2]) | (f2bf(acc[i][3]) << 16);
        *(uint2*)&Cb[((size_t)gs * M + r) * 64 + tc] = make_uint2(p0, p1);
      } else {
        *(float4*)&Cf[((size_t)gs * M + r) * 64 + tc] =
            make_float4(acc[i][0], acc[i][1], acc[i][2], acc[i][3]);
      }
    }
  }

  // fused attention sums (fp32 accumulator — exact)
  int u  = (bn + tc) / CH;
  int cc = tc % CH;
  const float* avs; const float* avd;
  if (CH == 64)       { avs = attAs + u * 64 + cc;           avd = attAd + u * 64 + cc; }
  else if (u < HEADS) { avs = attAs + u * 32 + cc;           avd = attAd + u * 32 + cc; }
  else                { avs = attBs + (u - HEADS) * 32 + cc; avd = attBd + (u - HEADS) * 32 + cc; }
  float w_s[4], w_d[4];
#pragma unroll
  for (int j = 0; j < 4; j++) { w_s[j] = avs[j]; w_d[j] = avd[j]; }
#pragma unroll
  for (int i = 0; i < 4; i++) {
    float ps = acc[i][0] * w_s[0] + acc[i][1] * w_s[1] + acc[i][2] * w_s[2] + acc[i][3] * w_s[3];
    float pd = acc[i][0] * w_d[0] + acc[i][1] * w_d[1] + acc[i][2] * w_d[2] + acc[i][3] * w_d[3];
#pragma unroll
    for (int o = 1; o < CH / 4; o <<= 1) {
      ps += __shfl_xor(ps, o);
      pd += __shfl_xor(pd, o);
    }
    int r = bm + tr + i;
    if (((tid & ((CH / 4) - 1)) == 0) && r < M) {
      as_out[(size_t)u * M + r] = ps;
      ad_out[(size_t)u * M + r] = pd;
    }
  }
}

// bf16-quad load helper: uint2 -> 4 floats
__device__ __forceinline__ void bf4(uint2 v, float& f0, float& f1, float& f2, float& f3) {
  f0 = __uint_as_float(v.x << 16);
  f1 = __uint_as_float(v.x & 0xffff0000u);
  f2 = __uint_as_float(v.y << 16);
  f3 = __uint_as_float(v.y & 0xffff0000u);
}

// ---------------- layer 1: block per node, 5 waves (wave = head), LDS reduce ----------------
// Gather reads bf16 xw rows (128 B/row, 16 lanes x uint2), 16 edges in flight,
// fully convergent tail. __shfl executed by ALL lanes (inactive-source
// ds_bpermute is undefined on CDNA — the R3-R5 bug).
__global__ __launch_bounds__(320) void agg1_k(const int* __restrict__ offs,
                                              const int* __restrict__ ssrc,
                                              const float* __restrict__ a_s,
                                              const float* __restrict__ a_d,
                                              const uint2* __restrict__ xwb,
                                              const float* __restrict__ b1,
                                              float* __restrict__ h1) {
  int n = blockIdx.x;
  int u = threadIdx.x >> 6;          // wave = head/unit
  int lane = threadIdx.x & 63;
  int off = offs[n], end = offs[n + 1];
  int deg = end - off;
  float ad = a_d[(size_t)u * N_NODES + n];
  const float* asl = a_s + (size_t)u * N_NODES;
  const uint2* xb  = xwb + (size_t)u * N_NODES * 16;   // slice u, 16 uint2/row
  int g = lane >> 4, q = lane & 15;
  float ax = 0.f, ay = 0.f, az = 0.f, aw = 0.f;

  if (deg <= 64) {
    int s = 0;
    float e = -1e30f;
    if (lane < deg) { s = ssrc[off + lane]; e = lrelu(asl[s] + ad); }
    float m = e;
#pragma unroll
    for (int o = 32; o > 0; o >>= 1) m = fmaxf(m, __shfl_xor(m, o));
    float p = (lane < deg) ? __expf(e - m) : 0.f;
    float den = p;
#pragma unroll
    for (int o = 32; o > 0; o >>= 1) den += __shfl_xor(den, o);
    float alpha = p * (1.f / (den + 1e-16f));

    for (int base = 0; base < deg; base += 16) {
      float alv[4];
      uint2 v[4];
#pragma unroll
      for (int t = 0; t < 4; t++) {
        int ee = base + t * 4 + g;
        bool ok = ee < deg;
        int es = ok ? ee : 0;                 // lane 0 always valid (self-loop)
        float alr = __shfl(alpha, es);        // all 64 lanes execute
        int   sv  = __shfl(s, es);
        alv[t] = ok ? alr : 0.f;
        v[t] = xb[(size_t)sv * 16 + q];       // unconditional
      }
#pragma unroll
      for (int t = 0; t < 4; t++) {
        float f0, f1, f2, f3;
        bf4(v[t], f0, f1, f2, f3);
        ax += alv[t] * f0; ay += alv[t] * f1;
        az += alv[t] * f2; aw += alv[t] * f3;
      }
    }
  } else {
    float m = -1e30f;
    for (int i = off + lane; i < end; i += 64) m = fmaxf(m, lrelu(asl[ssrc[i]] + ad));
#pragma unroll
    for (int o = 32; o > 0; o >>= 1) m = fmaxf(m, __shfl_xor(m, o));
    float den = 0.f;
    for (int i = off + lane; i < end; i += 64) den += __expf(lrelu(asl[ssrc[i]] + ad) - m);
#pragma unroll
    for (int o = 32; o > 0; o >>= 1) den += __shfl_xor(den, o);
    float inv = 1.f / (den + 1e-16f);
    for (int base = off; base < end; base += 4) {
      int e = base + g;
      if (e < end) {
        int sv = ssrc[e];
        float al = __expf(lrelu(asl[sv] + ad) - m) * inv;
        float f0, f1, f2, f3;
        bf4(xb[(size_t)sv * 16 + q], f0, f1, f2, f3);
        ax += al * f0; ay += al * f1; az += al * f2; aw += al * f3;
      }
    }
  }

#pragma unroll
  for (int o = 16; o < 64; o <<= 1) {
    ax += __shfl_xor(ax, o); ay += __shfl_xor(ay, o);
    az += __shfl_xor(az, o); aw += __shfl_xor(aw, o);
  }

  __shared__ float sacc[HEADS][64];
  if (g == 0) *(float4*)&sacc[u][q * 4] = make_float4(ax, ay, az, aw);
  __syncthreads();
  if (threadIdx.x < 64) {
    int t = threadIdx.x;
    float v = sacc[0][t] + sacc[1][t] + sacc[2][t] + sacc[3][t] + sacc[4][t];
    v = v * 0.2f + b1[t];
    h1[(size_t)n * 64 + t] = fmaxf(v, 0.f);
  }
}

// ---------------- layers 2+3: block per node, 5 waves (wave = pair 2g,2g+1) ----------------
__global__ __launch_bounds__(320) void agg23_k(const int* __restrict__ offs,
                                               const int* __restrict__ ssrc,
                                               const float* __restrict__ a_s,
                                               const float* __restrict__ a_d,
                                               const uint2* __restrict__ xwb,
                                               const float* __restrict__ b2,
                                               const float* __restrict__ b3,
                                               float* __restrict__ z_out,
                                               float* __restrict__ mu_out,
                                               float* __restrict__ lv_out) {
  int n = blockIdx.x;
  int gp = threadIdx.x >> 6;         // wave = pair index
  int lane = threadIdx.x & 63;
  int ulo = 2 * gp, uhi = 2 * gp + 1;
  int off = offs[n], end = offs[n + 1];
  int deg = end - off;
  float adlo = a_d[(size_t)ulo * N_NODES + n];
  float adhi = a_d[(size_t)uhi * N_NODES + n];
  const float* aslo = a_s + (size_t)ulo * N_NODES;
  const float* ashi = a_s + (size_t)uhi * N_NODES;
  const uint2* xb   = xwb + (size_t)gp * N_NODES * 16;
  int g = lane >> 4, q = lane & 15;
  float ax = 0.f, ay = 0.f, az = 0.f, aw = 0.f;

  if (deg <= 64) {
    int s = 0;
    float elo = -1e30f, ehi = -1e30f;
    if (lane < deg) {
      s = ssrc[off + lane];
      elo = lrelu(aslo[s] + adlo);
      ehi = lrelu(ashi[s] + adhi);
    }
    float mlo = elo, mhi = ehi;
#pragma unroll
    for (int o = 32; o > 0; o >>= 1) {
      mlo = fmaxf(mlo, __shfl_xor(mlo, o));
      mhi = fmaxf(mhi, __shfl_xor(mhi, o));
    }
    float plo = (lane < deg) ? __expf(elo - mlo) : 0.f;
    float phi = (lane < deg) ? __expf(ehi - mhi) : 0.f;
    float dlo = plo, dhi = phi;
#pragma unroll
    for (int o = 32; o > 0; o >>= 1) {
      dlo += __shfl_xor(dlo, o);
      dhi += __shfl_xor(dhi, o);
    }
    float allo = plo * (1.f / (dlo + 1e-16f));
    float alhi = phi * (1.f / (dhi + 1e-16f));

    for (int base = 0; base < deg; base += 16) {
      float alv[4];
      uint2 v[4];
#pragma unroll
      for (int t = 0; t < 4; t++) {
        int ee = base + t * 4 + g;
        bool ok = ee < deg;
        int es = ok ? ee : 0;                 // lane 0 always valid
        float a1 = __shfl(allo, es);          // all 64 lanes execute
        float a2 = __shfl(alhi, es);
        int   sv = __shfl(s, es);
        float alr = (q < 8) ? a1 : a2;
        alv[t] = ok ? alr : 0.f;
        v[t] = xb[(size_t)sv * 16 + q];       // unconditional
      }
#pragma unroll
      for (int t = 0; t < 4; t++) {
        float f0, f1, f2, f3;
        bf4(v[t], f0, f1, f2, f3);
        ax += alv[t] * f0; ay += alv[t] * f1;
        az += alv[t] * f2; aw += alv[t] * f3;
      }
    }
  } else {
    float mlo = -1e30f, mhi = -1e30f;
    for (int i = off + lane; i < end; i += 64) {
      int sv = ssrc[i];
      mlo = fmaxf(mlo, lrelu(aslo[sv] + adlo));
      mhi = fmaxf(mhi, lrelu(ashi[sv] + adhi));
    }
#pragma unroll
    for (int o = 32; o > 0; o >>= 1) {
      mlo = fmaxf(mlo, __shfl_xor(mlo, o));
      mhi = fmaxf(mhi, __shfl_xor(mhi, o));
    }
    float dlo = 0.f, dhi = 0.f;
    for (int i = off + lane; i < end; i += 64) {
      int sv = ssrc[i];
      dlo += __expf(lrelu(aslo[sv] + adlo) - mlo);
      dhi += __expf(lrelu(ashi[sv] + adhi) - mhi);
    }
#pragma unroll
    for (int o = 32; o > 0; o >>= 1) {
      dlo += __shfl_xor(dlo, o);
      dhi += __shfl_xor(dhi, o);
    }
    float ilo = 1.f / (dlo + 1e-16f), ihi = 1.f / (dhi + 1e-16f);
    for (int base = off; base < end; base += 4) {
      int e = base + g;
      if (e < end) {
        int sv = ssrc[e];
        float al;
        if (q < 8) al = __expf(lrelu(aslo[sv] + adlo) - mlo) * ilo;
        else       al = __expf(lrelu(ashi[sv] + adhi) - mhi) * ihi;
        float f0, f1, f2, f3;
        bf4(xb[(size_t)sv * 16 + q], f0, f1, f2, f3);
        ax += al * f0; ay += al * f1; az += al * f2; aw += al * f3;
      }
    }
  }

#pragma unroll
  for (int o = 16; o < 64; o <<= 1) {
    ax += __shfl_xor(ax, o); ay += __shfl_xor(ay, o);
    az += __shfl_xor(az, o); aw += __shfl_xor(aw, o);
  }

  __shared__ float sacc[HEADS][2][32];
  if (g == 0)
    *(float4*)&sacc[gp][q >> 3][(q & 7) * 4] = make_float4(ax, ay, az, aw);
  __syncthreads();
  if (threadIdx.x < 64) {
    int t = threadIdx.x;
    if (t < 32) {
      float v = sacc[0][0][t] + sacc[0][1][t] + sacc[1][0][t] + sacc[1][1][t] + sacc[2][0][t];
      v = v * 0.2f + b2[t];
      z_out[(size_t)n * 32 + t]  = v;
      mu_out[(size_t)n * 32 + t] = v;
    } else {
      int c = t - 32;
      float v = sacc[2][1][c] + sacc[3][0][c] + sacc[3][1][c] + sacc[4][0][c] + sacc[4][1][c];
      v = v * 0.2f + b3[c];
      lv_out[(size_t)n * 32 + c] = v;
    }
  }
}

// ---------------- launch ----------------
extern "C" void kernel_launch(void* const* d_in, const int* in_sizes, int n_in,
                              void* d_out, int out_size, void* d_ws, size_t ws_size,
                              hipStream_t stream) {
  const float* x        = (const float*)d_in[0];
  const int*   ei       = (const int*)d_in[1];
  const float* W1       = (const float*)d_in[2];
  const float* att_src1 = (const float*)d_in[3];
  const float* att_dst1 = (const float*)d_in[4];
  const float* b1       = (const float*)d_in[5];
  const float* W2       = (const float*)d_in[6];
  const float* att_src2 = (const float*)d_in[7];
  const float* att_dst2 = (const float*)d_in[8];
  const float* b2       = (const float*)d_in[9];
  const float* W3       = (const float*)d_in[10];
  const float* att_src3 = (const float*)d_in[11];
  const float* att_dst3 = (const float*)d_in[12];
  const float* b3       = (const float*)d_in[13];
  float* out = (float*)d_out;

  char* w = (char*)d_ws;
  auto alloc = [&](size_t bytes) -> void* {
    void* p = (void*)w;
    w += (bytes + 255) & ~(size_t)255;
    return p;
  };
  int*            deg    = (int*)alloc((size_t)N_NODES * 4);
  int*            offs   = (int*)alloc((size_t)(N_NODES + 1) * 4);
  int*            cursor = (int*)alloc((size_t)N_NODES * 4);
  int*            bsum   = (int*)alloc((size_t)128 * 4);
  int*            ssrc   = (int*)alloc((size_t)EP * 4);
  unsigned short* xwb    = (unsigned short*)alloc((size_t)N_NODES * 320 * 2);  // 12.8 MB bf16
  float*          a_s    = (float*)alloc((size_t)N_NODES * 10 * 4);
  float*          a_d    = (float*)alloc((size_t)N_NODES * 10 * 4);
  float*          h1     = (float*)alloc((size_t)N_NODES * 64 * 4);            // 5.12 MB
  float*          Wc     = (float*)alloc((size_t)64 * 320 * 4);
  // base total ~21 MB; fp32 xw (25.6 MB) allocated LAST, used only if it fits
  float*          xw     = (float*)alloc((size_t)N_NODES * 320 * 4);
  bool split = ((size_t)(w - (char*)d_ws) <= ws_size);   // deterministic per-run

  hipMemsetAsync(deg, 0, (size_t)N_NODES * 4, stream);
  hipMemsetAsync(cursor, 0, (size_t)N_NODES * 4, stream);

  int eb = (EP + 255) / 256;
  int nb = (N_NODES + 255) / 256;   // 79
  count_deg_k<<<eb, 256, 0, stream>>>(ei, deg);
  scan1_k<<<nb, 256, 0, stream>>>(deg, offs, bsum);
  scan2_k<<<1, 128, 0, stream>>>(bsum, nb);
  scan3_k<<<nb, 256, 0, stream>>>(offs, bsum);
  scatter_k<<<eb, 256, 0, stream>>>(ei, offs, cursor, ssrc);
  pack23_k<<<40, 256, 0, stream>>>(W2, W3, Wc);

  dim3 gg(313, 5);
  int n4 = N_NODES * 320 / 4;                 // 1.6M float4's
  int cb = (n4 + 255) / 256;

  if (split) {
    // fp32 GEMM (proven 40-VGPR kernel) -> convert -> bf16 gather
    sgemm_fused_k<64, false><<<gg, 256, 0, stream>>>(x, W1, xw, nullptr,
                                                     att_src1, att_dst1, nullptr, nullptr,
                                                     a_s, a_d, N_NODES, 320, 256);
    conv_bf16_k<<<cb, 256, 0, stream>>>((const float4*)xw, (uint2*)xwb, n4);
    agg1_k<<<N_NODES, 320, 0, stream>>>(offs, ssrc, a_s, a_d, (const uint2*)xwb, b1, h1);

    sgemm_fused_k<32, false><<<gg, 256, 0, stream>>>(h1, Wc, xw, nullptr,
                                                     att_src2, att_dst2, att_src3, att_dst3,
                                                     a_s, a_d, N_NODES, 320, 64);
    conv_bf16_k<<<cb, 256, 0, stream>>>((const float4*)xw, (uint2*)xwb, n4);
    agg23_k<<<N_NODES, 320, 0, stream>>>(offs, ssrc, a_s, a_d, (const uint2*)xwb, b2, b3,
                                         out, out + (size_t)N_NODES * 32,
                                         out + (size_t)2 * N_NODES * 32);
  } else {
    // fallback: direct bf16 store in GEMM (R11 path, ~268 us)
    sgemm_fused_k<64, true><<<gg, 256, 0, stream>>>(x, W1, nullptr, xwb,
                                                    att_src1, att_dst1, nullptr, nullptr,
                                                    a_s, a_d, N_NODES, 320, 256);
    agg1_k<<<N_NODES, 320, 0, stream>>>(offs, ssrc, a_s, a_d, (const uint2*)xwb, b1, h1);

    sgemm_fused_k<32, true><<<gg, 256, 0, stream>>>(h1, Wc, nullptr, xwb,
                                                    att_src2, att_dst2, att_src3, att_dst3,
                                                    a_s, a_d, N_NODES, 320, 64);
    agg23_k<<<N_NODES, 320, 0, stream>>>(offs, ssrc, a_s, a_d, (const uint2*)xwb, b2, b3,
                                         out, out + (size_t)N_NODES * 32,
                                         out + (size_t)2 * N_NODES * 32);
  }
}

// Round 14
// 206.279 us; speedup vs baseline: 6.4923x; 1.2855x over previous
//
#include <hip/hip_runtime.h>
#include <math.h>

#define N_NODES 20000
#define N_EDGES 320000
#define EP (N_EDGES + N_NODES)   // with self loops
#define HEADS 5

typedef __attribute__((ext_vector_type(8))) __bf16 bf16x8;
typedef __attribute__((ext_vector_type(4))) float f32x4;

__device__ __forceinline__ float lrelu(float s) { return (s > 0.f) ? s : 0.2f * s; }

// fp32 -> bf16 bits, round-to-nearest-even
__device__ __forceinline__ unsigned f2bf(float f) {
  unsigned u = __float_as_uint(f);
  return (u + 0x7fffu + ((u >> 16) & 1u)) >> 16;
}

// ---------------- CSR build ----------------
__global__ void count_deg_k(const int* __restrict__ ei, int* __restrict__ deg) {
  int e = blockIdx.x * blockDim.x + threadIdx.x;
  if (e >= EP) return;
  int dst = (e < N_EDGES) ? ei[N_EDGES + e] : (e - N_EDGES);
  atomicAdd(&deg[dst], 1);
}

__global__ __launch_bounds__(256) void scan1_k(const int* __restrict__ deg,
                                               int* __restrict__ offs,
                                               int* __restrict__ bsum) {
  __shared__ int buf[256];
  int tid = threadIdx.x, i = blockIdx.x * 256 + tid;
  int v = (i < N_NODES) ? deg[i] : 0;
  buf[tid] = v;
  __syncthreads();
  for (int o = 1; o < 256; o <<= 1) {
    int t = (tid >= o) ? buf[tid - o] : 0;
    __syncthreads();
    buf[tid] += t;
    __syncthreads();
  }
  if (i < N_NODES) offs[i] = buf[tid] - v;   // block-local exclusive
  if (tid == 255) bsum[blockIdx.x] = buf[255];
}

__global__ __launch_bounds__(128) void scan2_k(int* __restrict__ bsum, int nb) {
  __shared__ int buf[128];
  int tid = threadIdx.x;
  int v = (tid < nb) ? bsum[tid] : 0;
  buf[tid] = v;
  __syncthreads();
  for (int o = 1; o < 128; o <<= 1) {
    int t = (tid >= o) ? buf[tid - o] : 0;
    __syncthreads();
    buf[tid] += t;
    __syncthreads();
  }
  if (tid < nb) bsum[tid] = buf[tid] - v;    // exclusive
}

__global__ void scan3_k(int* __restrict__ offs, const int* __restrict__ bsum) {
  int i = blockIdx.x * 256 + threadIdx.x;
  if (i < N_NODES) offs[i] += bsum[blockIdx.x];
  if (i == 0) offs[N_NODES] = EP;
}

__global__ void scatter_k(const int* __restrict__ ei, const int* __restrict__ offs,
                          int* __restrict__ cursor, int* __restrict__ ssrc) {
  int e = blockIdx.x * blockDim.x + threadIdx.x;
  if (e >= EP) return;
  int src, dst;
  if (e < N_EDGES) { src = ei[e]; dst = ei[N_EDGES + e]; }
  else             { src = e - N_EDGES; dst = src; }
  int pos = atomicAdd(&cursor[dst], 1);
  ssrc[offs[dst] + pos] = src;
}

// ---------------- fp32 -> bf16 convert (elementwise, float4 -> uint2) ----------------
__global__ __launch_bounds__(256) void conv_bf16_k(const float4* __restrict__ src,
                                                   uint2* __restrict__ dst, int n4) {
  int t = blockIdx.x * blockDim.x + threadIdx.x;
  if (t >= n4) return;
  float4 v = src[t];
  unsigned p0 = f2bf(v.x) | (f2bf(v.y) << 16);
  unsigned p1 = f2bf(v.z) | (f2bf(v.w) << 16);
  dst[t] = make_uint2(p0, p1);
}

// ---------------- pack W1[256][320] -> MFMA B-fragment order, bf16 ----------------
// Wp[gnt(20)][ks(8)][lane(64)][i(8)]; B layout: col = lane&15, k = (lane>>4)*8 + i
__global__ void packW1_k(const float* __restrict__ W, unsigned short* __restrict__ Wp) {
  int t = blockIdx.x * blockDim.x + threadIdx.x;
  if (t >= 256 * 320) return;
  int k = t / 320, n = t % 320;
  int gnt = n >> 4, ll = n & 15;
  int ks = k >> 5, kr = k & 31;
  int lh = kr >> 3, i = kr & 7;
  Wp[(((size_t)gnt * 8 + ks) * 64 + lh * 16 + ll) * 8 + i] = (unsigned short)f2bf(W[t]);
}

// ---------------- pack [W2|W3] (64x320 combined) -> fragment order, bf16 ----------------
// combined col n: unit u=n/32 (u<5 -> W2 head u, else W3 head u-5), c=n%32
__global__ void packW23_k(const float* __restrict__ W2, const float* __restrict__ W3,
                          unsigned short* __restrict__ Wp) {
  int t = blockIdx.x * blockDim.x + threadIdx.x;
  if (t >= 64 * 320) return;
  int k = t / 320, n = t % 320;
  int u = n / 32, c = n % 32;
  float val = (u < HEADS) ? W2[k * 160 + u * 32 + c] : W3[k * 160 + (u - HEADS) * 32 + c];
  int gnt = n >> 4, ll = n & 15;
  int ks = k >> 5, kr = k & 31;
  int lh = kr >> 3, i = kr & 7;
  Wp[(((size_t)gnt * 2 + ks) * 64 + lh * 16 + ll) * 8 + i] = (unsigned short)f2bf(val);
}

// ---------------- MFMA GEMM (bf16 in, fp32 acc) + fused att-sums ----------------
// A[M][K] bf16 row-major; Bp packed frags; C bf16 in 64-col slices
// Cb[(panel*M + r)*64 + (col-panel*64)]. Block = 64 rows x 64 cols, 4 waves,
// wave w = rows [bm+w*16, +16), 4 col-tiles. NO LDS, NO barriers.
// MFMA 16x16x32_bf16: A-frag lane l: row=l&15, k=(l>>4)*8+i.
//                     B-frag lane l: col=l&15, k=(l>>4)*8+i.
//                     C/D:  lane l reg j: col=l&15, row=(l>>4)*4+j  [verified m89]
template <int KSTEPS, int CH>
__global__ __launch_bounds__(256) void mfma_gemm_k(
    const unsigned short* __restrict__ A, const unsigned short* __restrict__ Bp,
    unsigned short* __restrict__ Cb,
    const float* __restrict__ attAs, const float* __restrict__ attAd,
    const float* __restrict__ attBs, const float* __restrict__ attBd,
    float* __restrict__ as_out, float* __restrict__ ad_out, int M) {
  constexpr int K = KSTEPS * 32;
  int bm = blockIdx.x * 64;
  int panel = blockIdx.y;
  int w = threadIdx.x >> 6;
  int l = threadIdx.x & 63;
  int ll = l & 15, lh = l >> 4;

  int arow = bm + w * 16 + ll;
  if (arow >= M) arow = M - 1;          // clamp; writes are guarded
  const unsigned short* ap = A + (size_t)arow * K + lh * 8;

  f32x4 acc[4] = {};
  for (int ks = 0; ks < KSTEPS; ks++) {
    bf16x8 af = *(const bf16x8*)(ap + ks * 32);
#pragma unroll
    for (int nt = 0; nt < 4; nt++) {
      bf16x8 bf = *(const bf16x8*)(Bp + (((size_t)(panel * 4 + nt) * KSTEPS + ks) * 64 + l) * 8);
      acc[nt] = __builtin_amdgcn_mfma_f32_16x16x32_bf16(af, bf, acc[nt], 0, 0, 0);
    }
  }

  // C write (bf16, slice layout)
  int row0 = bm + w * 16 + lh * 4;
#pragma unroll
  for (int j = 0; j < 4; j++) {
    int r = row0 + j;
    if (r < M) {
#pragma unroll
      for (int nt = 0; nt < 4; nt++)
        Cb[((size_t)panel * M + r) * 64 + nt * 16 + ll] = (unsigned short)f2bf(acc[nt][j]);
    }
  }

  // fused attention sums: reduce over cols (16-lane butterfly per l>>4 group)
  float ws[4], wd[4];
  if (CH == 64) {
#pragma unroll
    for (int nt = 0; nt < 4; nt++) {
      ws[nt] = attAs[panel * 64 + nt * 16 + ll];
      wd[nt] = attAd[panel * 64 + nt * 16 + ll];
    }
  } else {
#pragma unroll
    for (int nt = 0; nt < 4; nt++) {
      int u = panel * 2 + (nt >> 1);
      int c = (nt & 1) * 16 + ll;
      const float* s = (u < HEADS) ? attAs + u * 32 : attBs + (u - HEADS) * 32;
      const float* d = (u < HEADS) ? attAd + u * 32 : attBd + (u - HEADS) * 32;
      ws[nt] = s[c]; wd[nt] = d[c];
    }
  }
#pragma unroll
  for (int j = 0; j < 4; j++) {
    int r = row0 + j;
    if (CH == 64) {
      float ps = acc[0][j] * ws[0] + acc[1][j] * ws[1] + acc[2][j] * ws[2] + acc[3][j] * ws[3];
      float pd = acc[0][j] * wd[0] + acc[1][j] * wd[1] + acc[2][j] * wd[2] + acc[3][j] * wd[3];
#pragma unroll
      for (int o = 1; o < 16; o <<= 1) {
        ps += __shfl_xor(ps, o);
        pd += __shfl_xor(pd, o);
      }
      if (ll == 0 && r < M) {
        as_out[(size_t)panel * M + r] = ps;
        ad_out[(size_t)panel * M + r] = pd;
      }
    } else {
      float ls = acc[0][j] * ws[0] + acc[1][j] * ws[1];
      float ld = acc[0][j] * wd[0] + acc[1][j] * wd[1];
      float hs = acc[2][j] * ws[2] + acc[3][j] * ws[3];
      float hd = acc[2][j] * wd[2] + acc[3][j] * wd[3];
#pragma unroll
      for (int o = 1; o < 16; o <<= 1) {
        ls += __shfl_xor(ls, o); ld += __shfl_xor(ld, o);
        hs += __shfl_xor(hs, o); hd += __shfl_xor(hd, o);
      }
      if (ll == 0 && r < M) {
        int ulo = panel * 2, uhi = panel * 2 + 1;
        as_out[(size_t)ulo * M + r] = ls;  ad_out[(size_t)ulo * M + r] = ld;
        as_out[(size_t)uhi * M + r] = hs;  ad_out[(size_t)uhi * M + r] = hd;
      }
    }
  }
}

// bf16-quad load helper: uint2 -> 4 floats
__device__ __forceinline__ void bf4(uint2 v, float& f0, float& f1, float& f2, float& f3) {
  f0 = __uint_as_float(v.x << 16);
  f1 = __uint_as_float(v.x & 0xffff0000u);
  f2 = __uint_as_float(v.y << 16);
  f3 = __uint_as_float(v.y & 0xffff0000u);
}

// ---------------- layer 1: block per node, 5 waves (wave = head), LDS reduce ----------------
// h1 written as bf16 (layer-2 MFMA A-operand). Gather: bf16 rows, 16 edges in
// flight, convergent tail; __shfl by ALL lanes (inactive-source ds_bpermute
// undefined on CDNA — R3-R5 bug).
__global__ __launch_bounds__(320) void agg1_k(const int* __restrict__ offs,
                                              const int* __restrict__ ssrc,
                                              const float* __restrict__ a_s,
                                              const float* __restrict__ a_d,
                                              const uint2* __restrict__ xwb,
                                              const float* __restrict__ b1,
                                              unsigned short* __restrict__ h1b) {
  int n = blockIdx.x;
  int u = threadIdx.x >> 6;
  int lane = threadIdx.x & 63;
  int off = offs[n], end = offs[n + 1];
  int deg = end - off;
  float ad = a_d[(size_t)u * N_NODES + n];
  const float* asl = a_s + (size_t)u * N_NODES;
  const uint2* xb  = xwb + (size_t)u * N_NODES * 16;
  int g = lane >> 4, q = lane & 15;
  float ax = 0.f, ay = 0.f, az = 0.f, aw = 0.f;

  if (deg <= 64) {
    int s = 0;
    float e = -1e30f;
    if (lane < deg) { s = ssrc[off + lane]; e = lrelu(asl[s] + ad); }
    float m = e;
#pragma unroll
    for (int o = 32; o > 0; o >>= 1) m = fmaxf(m, __shfl_xor(m, o));
    float p = (lane < deg) ? __expf(e - m) : 0.f;
    float den = p;
#pragma unroll
    for (int o = 32; o > 0; o >>= 1) den += __shfl_xor(den, o);
    float alpha = p * (1.f / (den + 1e-16f));

    for (int base = 0; base < deg; base += 16) {
      float alv[4];
      uint2 v[4];
#pragma unroll
      for (int t = 0; t < 4; t++) {
        int ee = base + t * 4 + g;
        bool ok = ee < deg;
        int es = ok ? ee : 0;
        float alr = __shfl(alpha, es);
        int   sv  = __shfl(s, es);
        alv[t] = ok ? alr : 0.f;
        v[t] = xb[(size_t)sv * 16 + q];
      }
#pragma unroll
      for (int t = 0; t < 4; t++) {
        float f0, f1, f2, f3;
        bf4(v[t], f0, f1, f2, f3);
        ax += alv[t] * f0; ay += alv[t] * f1;
        az += alv[t] * f2; aw += alv[t] * f3;
      }
    }
  } else {
    float m = -1e30f;
    for (int i = off + lane; i < end; i += 64) m = fmaxf(m, lrelu(asl[ssrc[i]] + ad));
#pragma unroll
    for (int o = 32; o > 0; o >>= 1) m = fmaxf(m, __shfl_xor(m, o));
    float den = 0.f;
    for (int i = off + lane; i < end; i += 64) den += __expf(lrelu(asl[ssrc[i]] + ad) - m);
#pragma unroll
    for (int o = 32; o > 0; o >>= 1) den += __shfl_xor(den, o);
    float inv = 1.f / (den + 1e-16f);
    for (int base = off; base < end; base += 4) {
      int e = base + g;
      if (e < end) {
        int sv = ssrc[e];
        float al = __expf(lrelu(asl[sv] + ad) - m) * inv;
        float f0, f1, f2, f3;
        bf4(xb[(size_t)sv * 16 + q], f0, f1, f2, f3);
        ax += al * f0; ay += al * f1; az += al * f2; aw += al * f3;
      }
    }
  }

#pragma unroll
  for (int o = 16; o < 64; o <<= 1) {
    ax += __shfl_xor(ax, o); ay += __shfl_xor(ay, o);
    az += __shfl_xor(az, o); aw += __shfl_xor(aw, o);
  }

  __shared__ float sacc[HEADS][64];
  if (g == 0) *(float4*)&sacc[u][q * 4] = make_float4(ax, ay, az, aw);
  __syncthreads();
  if (threadIdx.x < 64) {
    int t = threadIdx.x;
    float v = sacc[0][t] + sacc[1][t] + sacc[2][t] + sacc[3][t] + sacc[4][t];
    v = fmaxf(v * 0.2f + b1[t], 0.f);
    h1b[(size_t)n * 64 + t] = (unsigned short)f2bf(v);
  }
}

// ---------------- layers 2+3: block per node, 5 waves (wave = pair 2g,2g+1) ----------------
__global__ __launch_bounds__(320) void agg23_k(const int* __restrict__ offs,
                                               const int* __restrict__ ssrc,
                                               const float* __restrict__ a_s,
                                               const float* __restrict__ a_d,
                                               const uint2* __restrict__ xwb,
                                               const float* __restrict__ b2,
                                               const float* __restrict__ b3,
                                               float* __restrict__ z_out,
                                               float* __restrict__ mu_out,
                                               float* __restrict__ lv_out) {
  int n = blockIdx.x;
  int gp = threadIdx.x >> 6;
  int lane = threadIdx.x & 63;
  int ulo = 2 * gp, uhi = 2 * gp + 1;
  int off = offs[n], end = offs[n + 1];
  int deg = end - off;
  float adlo = a_d[(size_t)ulo * N_NODES + n];
  float adhi = a_d[(size_t)uhi * N_NODES + n];
  const float* aslo = a_s + (size_t)ulo * N_NODES;
  const float* ashi = a_s + (size_t)uhi * N_NODES;
  const uint2* xb   = xwb + (size_t)gp * N_NODES * 16;
  int g = lane >> 4, q = lane & 15;
  float ax = 0.f, ay = 0.f, az = 0.f, aw = 0.f;

  if (deg <= 64) {
    int s = 0;
    float elo = -1e30f, ehi = -1e30f;
    if (lane < deg) {
      s = ssrc[off + lane];
      elo = lrelu(aslo[s] + adlo);
      ehi = lrelu(ashi[s] + adhi);
    }
    float mlo = elo, mhi = ehi;
#pragma unroll
    for (int o = 32; o > 0; o >>= 1) {
      mlo = fmaxf(mlo, __shfl_xor(mlo, o));
      mhi = fmaxf(mhi, __shfl_xor(mhi, o));
    }
    float plo = (lane < deg) ? __expf(elo - mlo) : 0.f;
    float phi = (lane < deg) ? __expf(ehi - mhi) : 0.f;
    float dlo = plo, dhi = phi;
#pragma unroll
    for (int o = 32; o > 0; o >>= 1) {
      dlo += __shfl_xor(dlo, o);
      dhi += __shfl_xor(dhi, o);
    }
    float allo = plo * (1.f / (dlo + 1e-16f));
    float alhi = phi * (1.f / (dhi + 1e-16f));

    for (int base = 0; base < deg; base += 16) {
      float alv[4];
      uint2 v[4];
#pragma unroll
      for (int t = 0; t < 4; t++) {
        int ee = base + t * 4 + g;
        bool ok = ee < deg;
        int es = ok ? ee : 0;
        float a1 = __shfl(allo, es);
        float a2 = __shfl(alhi, es);
        int   sv = __shfl(s, es);
        float alr = (q < 8) ? a1 : a2;
        alv[t] = ok ? alr : 0.f;
        v[t] = xb[(size_t)sv * 16 + q];
      }
#pragma unroll
      for (int t = 0; t < 4; t++) {
        float f0, f1, f2, f3;
        bf4(v[t], f0, f1, f2, f3);
        ax += alv[t] * f0; ay += alv[t] * f1;
        az += alv[t] * f2; aw += alv[t] * f3;
      }
    }
  } else {
    float mlo = -1e30f, mhi = -1e30f;
    for (int i = off + lane; i < end; i += 64) {
      int sv = ssrc[i];
      mlo = fmaxf(mlo, lrelu(aslo[sv] + adlo));
      mhi = fmaxf(mhi, lrelu(ashi[sv] + adhi));
    }
#pragma unroll
    for (int o = 32; o > 0; o >>= 1) {
      mlo = fmaxf(mlo, __shfl_xor(mlo, o));
      mhi = fmaxf(mhi, __shfl_xor(mhi, o));
    }
    float dlo = 0.f, dhi = 0.f;
    for (int i = off + lane; i < end; i += 64) {
      int sv = ssrc[i];
      dlo += __expf(lrelu(aslo[sv] + adlo) - mlo);
      dhi += __expf(lrelu(ashi[sv] + adhi) - mhi);
    }
#pragma unroll
    for (int o = 32; o > 0; o >>= 1) {
      dlo += __shfl_xor(dlo, o);
      dhi += __shfl_xor(dhi, o);
    }
    float ilo = 1.f / (dlo + 1e-16f), ihi = 1.f / (dhi + 1e-16f);
    for (int base = off; base < end; base += 4) {
      int e = base + g;
      if (e < end) {
        int sv = ssrc[e];
        float al;
        if (q < 8) al = __expf(lrelu(aslo[sv] + adlo) - mlo) * ilo;
        else       al = __expf(lrelu(ashi[sv] + adhi) - mhi) * ihi;
        float f0, f1, f2, f3;
        bf4(xb[(size_t)sv * 16 + q], f0, f1, f2, f3);
        ax += al * f0; ay += al * f1; az += al * f2; aw += al * f3;
      }
    }
  }

#pragma unroll
  for (int o = 16; o < 64; o <<= 1) {
    ax += __shfl_xor(ax, o); ay += __shfl_xor(ay, o);
    az += __shfl_xor(az, o); aw += __shfl_xor(aw, o);
  }

  __shared__ float sacc[HEADS][2][32];
  if (g == 0)
    *(float4*)&sacc[gp][q >> 3][(q & 7) * 4] = make_float4(ax, ay, az, aw);
  __syncthreads();
  if (threadIdx.x < 64) {
    int t = threadIdx.x;
    if (t < 32) {
      float v = sacc[0][0][t] + sacc[0][1][t] + sacc[1][0][t] + sacc[1][1][t] + sacc[2][0][t];
      v = v * 0.2f + b2[t];
      z_out[(size_t)n * 32 + t]  = v;
      mu_out[(size_t)n * 32 + t] = v;
    } else {
      int c = t - 32;
      float v = sacc[2][1][c] + sacc[3][0][c] + sacc[3][1][c] + sacc[4][0][c] + sacc[4][1][c];
      v = v * 0.2f + b3[c];
      lv_out[(size_t)n * 32 + c] = v;
    }
  }
}

// ---------------- launch ----------------
extern "C" void kernel_launch(void* const* d_in, const int* in_sizes, int n_in,
                              void* d_out, int out_size, void* d_ws, size_t ws_size,
                              hipStream_t stream) {
  const float* x        = (const float*)d_in[0];
  const int*   ei       = (const int*)d_in[1];
  const float* W1       = (const float*)d_in[2];
  const float* att_src1 = (const float*)d_in[3];
  const float* att_dst1 = (const float*)d_in[4];
  const float* b1       = (const float*)d_in[5];
  const float* W2       = (const float*)d_in[6];
  const float* att_src2 = (const float*)d_in[7];
  const float* att_dst2 = (const float*)d_in[8];
  const float* b2       = (const float*)d_in[9];
  const float* W3       = (const float*)d_in[10];
  const float* att_src3 = (const float*)d_in[11];
  const float* att_dst3 = (const float*)d_in[12];
  const float* b3       = (const float*)d_in[13];
  float* out = (float*)d_out;

  char* w = (char*)d_ws;
  auto alloc = [&](size_t bytes) -> void* {
    void* p = (void*)w;
    w += (bytes + 255) & ~(size_t)255;
    return p;
  };
  int*            deg    = (int*)alloc((size_t)N_NODES * 4);
  int*            offs   = (int*)alloc((size_t)(N_NODES + 1) * 4);
  int*            cursor = (int*)alloc((size_t)N_NODES * 4);
  int*            bsum   = (int*)alloc((size_t)128 * 4);
  int*            ssrc   = (int*)alloc((size_t)EP * 4);
  unsigned short* xwb    = (unsigned short*)alloc((size_t)N_NODES * 320 * 2);  // 12.8 MB
  float*          a_s    = (float*)alloc((size_t)N_NODES * 10 * 4);
  float*          a_d    = (float*)alloc((size_t)N_NODES * 10 * 4);
  unsigned short* h1b    = (unsigned short*)alloc((size_t)N_NODES * 64 * 2);   // 2.56 MB
  unsigned short* xbf    = (unsigned short*)alloc((size_t)N_NODES * 256 * 2);  // 10.24 MB
  unsigned short* Wp1    = (unsigned short*)alloc((size_t)256 * 320 * 2);
  unsigned short* Wp23   = (unsigned short*)alloc((size_t)64 * 320 * 2);
  // total ~29 MB (< proven ~34 MB)

  hipMemsetAsync(deg, 0, (size_t)N_NODES * 4, stream);
  hipMemsetAsync(cursor, 0, (size_t)N_NODES * 4, stream);

  int eb = (EP + 255) / 256;
  int nb = (N_NODES + 255) / 256;   // 79
  count_deg_k<<<eb, 256, 0, stream>>>(ei, deg);
  scan1_k<<<nb, 256, 0, stream>>>(deg, offs, bsum);
  scan2_k<<<1, 128, 0, stream>>>(bsum, nb);
  scan3_k<<<nb, 256, 0, stream>>>(offs, bsum);
  scatter_k<<<eb, 256, 0, stream>>>(ei, offs, cursor, ssrc);

  int nx4 = N_NODES * 256 / 4;
  conv_bf16_k<<<(nx4 + 255) / 256, 256, 0, stream>>>((const float4*)x, (uint2*)xbf, nx4);
  packW1_k<<<(256 * 320 + 255) / 256, 256, 0, stream>>>(W1, Wp1);
  packW23_k<<<(64 * 320 + 255) / 256, 256, 0, stream>>>(W2, W3, Wp23);

  dim3 gg(313, 5);

  // ---- layer 1 ----
  mfma_gemm_k<8, 64><<<gg, 256, 0, stream>>>(xbf, Wp1, xwb,
                                             att_src1, att_dst1, nullptr, nullptr,
                                             a_s, a_d, N_NODES);
  agg1_k<<<N_NODES, 320, 0, stream>>>(offs, ssrc, a_s, a_d, (const uint2*)xwb, b1, h1b);

  // ---- layers 2+3 fused ----
  mfma_gemm_k<2, 32><<<gg, 256, 0, stream>>>(h1b, Wp23, xwb,
                                             att_src2, att_dst2, att_src3, att_dst3,
                                             a_s, a_d, N_NODES);
  agg23_k<<<N_NODES, 320, 0, stream>>>(offs, ssrc, a_s, a_d, (const uint2*)xwb, b2, b3,
                                       out, out + (size_t)N_NODES * 32,
                                       out + (size_t)2 * N_NODES * 32);
}

// Round 15
// 205.494 us; speedup vs baseline: 6.5171x; 1.0038x over previous
//
#include <hip/hip_runtime.h>
#include <math.h>

#define N_NODES 20000
#define N_EDGES 320000
#define EP (N_EDGES + N_NODES)   // with self loops
#define HEADS 5

typedef __attribute__((ext_vector_type(8))) __bf16 bf16x8;
typedef __attribute__((ext_vector_type(4))) float f32x4;

__device__ __forceinline__ float lrelu(float s) { return (s > 0.f) ? s : 0.2f * s; }

// fp32 -> bf16 bits, round-to-nearest-even
__device__ __forceinline__ unsigned f2bf(float f) {
  unsigned u = __float_as_uint(f);
  return (u + 0x7fffu + ((u >> 16) & 1u)) >> 16;
}

// ---------------- CSR build ----------------
__global__ void count_deg_k(const int* __restrict__ ei, int* __restrict__ deg) {
  int e = blockIdx.x * blockDim.x + threadIdx.x;
  if (e >= EP) return;
  int dst = (e < N_EDGES) ? ei[N_EDGES + e] : (e - N_EDGES);
  atomicAdd(&deg[dst], 1);
}

__global__ __launch_bounds__(256) void scan1_k(const int* __restrict__ deg,
                                               int* __restrict__ offs,
                                               int* __restrict__ bsum) {
  __shared__ int buf[256];
  int tid = threadIdx.x, i = blockIdx.x * 256 + tid;
  int v = (i < N_NODES) ? deg[i] : 0;
  buf[tid] = v;
  __syncthreads();
  for (int o = 1; o < 256; o <<= 1) {
    int t = (tid >= o) ? buf[tid - o] : 0;
    __syncthreads();
    buf[tid] += t;
    __syncthreads();
  }
  if (i < N_NODES) offs[i] = buf[tid] - v;   // block-local exclusive
  if (tid == 255) bsum[blockIdx.x] = buf[255];
}

__global__ __launch_bounds__(128) void scan2_k(int* __restrict__ bsum, int nb) {
  __shared__ int buf[128];
  int tid = threadIdx.x;
  int v = (tid < nb) ? bsum[tid] : 0;
  buf[tid] = v;
  __syncthreads();
  for (int o = 1; o < 128; o <<= 1) {
    int t = (tid >= o) ? buf[tid - o] : 0;
    __syncthreads();
    buf[tid] += t;
    __syncthreads();
  }
  if (tid < nb) bsum[tid] = buf[tid] - v;    // exclusive
}

__global__ void scan3_k(int* __restrict__ offs, const int* __restrict__ bsum) {
  int i = blockIdx.x * 256 + threadIdx.x;
  if (i < N_NODES) offs[i] += bsum[blockIdx.x];
  if (i == 0) offs[N_NODES] = EP;
}

__global__ void scatter_k(const int* __restrict__ ei, const int* __restrict__ offs,
                          int* __restrict__ cursor, int* __restrict__ ssrc) {
  int e = blockIdx.x * blockDim.x + threadIdx.x;
  if (e >= EP) return;
  int src, dst;
  if (e < N_EDGES) { src = ei[e]; dst = ei[N_EDGES + e]; }
  else             { src = e - N_EDGES; dst = src; }
  int pos = atomicAdd(&cursor[dst], 1);
  ssrc[offs[dst] + pos] = src;
}

// ---------------- fp32 -> bf16 convert (elementwise, float4 -> uint2) ----------------
__global__ __launch_bounds__(256) void conv_bf16_k(const float4* __restrict__ src,
                                                   uint2* __restrict__ dst, int n4) {
  int t = blockIdx.x * blockDim.x + threadIdx.x;
  if (t >= n4) return;
  float4 v = src[t];
  unsigned p0 = f2bf(v.x) | (f2bf(v.y) << 16);
  unsigned p1 = f2bf(v.z) | (f2bf(v.w) << 16);
  dst[t] = make_uint2(p0, p1);
}

// ---------------- pack W1[256][320] -> MFMA B-fragment order, bf16 ----------------
// Wp[gnt(20)][ks(8)][lane(64)][i(8)]; B layout: col = lane&15, k = (lane>>4)*8 + i
__global__ void packW1_k(const float* __restrict__ W, unsigned short* __restrict__ Wp) {
  int t = blockIdx.x * blockDim.x + threadIdx.x;
  if (t >= 256 * 320) return;
  int k = t / 320, n = t % 320;
  int gnt = n >> 4, ll = n & 15;
  int ks = k >> 5, kr = k & 31;
  int lh = kr >> 3, i = kr & 7;
  Wp[(((size_t)gnt * 8 + ks) * 64 + lh * 16 + ll) * 8 + i] = (unsigned short)f2bf(W[t]);
}

// ---------------- pack [W2|W3] (64x320 combined) -> fragment order, bf16 ----------------
__global__ void packW23_k(const float* __restrict__ W2, const float* __restrict__ W3,
                          unsigned short* __restrict__ Wp) {
  int t = blockIdx.x * blockDim.x + threadIdx.x;
  if (t >= 64 * 320) return;
  int k = t / 320, n = t % 320;
  int u = n / 32, c = n % 32;
  float val = (u < HEADS) ? W2[k * 160 + u * 32 + c] : W3[k * 160 + (u - HEADS) * 32 + c];
  int gnt = n >> 4, ll = n & 15;
  int ks = k >> 5, kr = k & 31;
  int lh = kr >> 3, i = kr & 7;
  Wp[(((size_t)gnt * 2 + ks) * 64 + lh * 16 + ll) * 8 + i] = (unsigned short)f2bf(val);
}

// ---------------- MFMA GEMM (bf16 in, fp32 acc) + fused att-sums ----------------
// Grid (5, 313): panel = blockIdx.x (FAST), row-tile = blockIdx.y -> the 5
// panels sharing an A row-tile are consecutive blocks (A reused from L2;
// was 51 MB of A re-streaming with the old (313,5) order).
// Block = 64 rows x 64 cols, 4 waves, NO LDS, NO barriers.
// MFMA 16x16x32_bf16: A lane l: row=l&15, k=(l>>4)*8+i; B: col=l&15, same k;
// C/D lane l reg j: col=l&15, row=(l>>4)*4+j  [verified m89]
template <int KSTEPS, int CH>
__global__ __launch_bounds__(256) void mfma_gemm_k(
    const unsigned short* __restrict__ A, const unsigned short* __restrict__ Bp,
    unsigned short* __restrict__ Cb,
    const float* __restrict__ attAs, const float* __restrict__ attAd,
    const float* __restrict__ attBs, const float* __restrict__ attBd,
    float* __restrict__ as_out, float* __restrict__ ad_out, int M) {
  constexpr int K = KSTEPS * 32;
  int panel = blockIdx.x;
  int bm = blockIdx.y * 64;
  int w = threadIdx.x >> 6;
  int l = threadIdx.x & 63;
  int ll = l & 15, lh = l >> 4;

  int arow = bm + w * 16 + ll;
  if (arow >= M) arow = M - 1;          // clamp; writes are guarded
  const unsigned short* ap = A + (size_t)arow * K + lh * 8;

  f32x4 acc[4] = {};
  for (int ks = 0; ks < KSTEPS; ks++) {
    bf16x8 af = *(const bf16x8*)(ap + ks * 32);
#pragma unroll
    for (int nt = 0; nt < 4; nt++) {
      bf16x8 bf = *(const bf16x8*)(Bp + (((size_t)(panel * 4 + nt) * KSTEPS + ks) * 64 + l) * 8);
      acc[nt] = __builtin_amdgcn_mfma_f32_16x16x32_bf16(af, bf, acc[nt], 0, 0, 0);
    }
  }

  // C write (bf16, slice layout)
  int row0 = bm + w * 16 + lh * 4;
#pragma unroll
  for (int j = 0; j < 4; j++) {
    int r = row0 + j;
    if (r < M) {
#pragma unroll
      for (int nt = 0; nt < 4; nt++)
        Cb[((size_t)panel * M + r) * 64 + nt * 16 + ll] = (unsigned short)f2bf(acc[nt][j]);
    }
  }

  // fused attention sums: reduce over cols (16-lane butterfly per l>>4 group)
  float ws[4], wd[4];
  if (CH == 64) {
#pragma unroll
    for (int nt = 0; nt < 4; nt++) {
      ws[nt] = attAs[panel * 64 + nt * 16 + ll];
      wd[nt] = attAd[panel * 64 + nt * 16 + ll];
    }
  } else {
#pragma unroll
    for (int nt = 0; nt < 4; nt++) {
      int u = panel * 2 + (nt >> 1);
      int c = (nt & 1) * 16 + ll;
      const float* s = (u < HEADS) ? attAs + u * 32 : attBs + (u - HEADS) * 32;
      const float* d = (u < HEADS) ? attAd + u * 32 : attBd + (u - HEADS) * 32;
      ws[nt] = s[c]; wd[nt] = d[c];
    }
  }
#pragma unroll
  for (int j = 0; j < 4; j++) {
    int r = row0 + j;
    if (CH == 64) {
      float ps = acc[0][j] * ws[0] + acc[1][j] * ws[1] + acc[2][j] * ws[2] + acc[3][j] * ws[3];
      float pd = acc[0][j] * wd[0] + acc[1][j] * wd[1] + acc[2][j] * wd[2] + acc[3][j] * wd[3];
#pragma unroll
      for (int o = 1; o < 16; o <<= 1) {
        ps += __shfl_xor(ps, o);
        pd += __shfl_xor(pd, o);
      }
      if (ll == 0 && r < M) {
        as_out[(size_t)panel * M + r] = ps;
        ad_out[(size_t)panel * M + r] = pd;
      }
    } else {
      float ls = acc[0][j] * ws[0] + acc[1][j] * ws[1];
      float ld = acc[0][j] * wd[0] + acc[1][j] * wd[1];
      float hs = acc[2][j] * ws[2] + acc[3][j] * ws[3];
      float hd = acc[2][j] * wd[2] + acc[3][j] * wd[3];
#pragma unroll
      for (int o = 1; o < 16; o <<= 1) {
        ls += __shfl_xor(ls, o); ld += __shfl_xor(ld, o);
        hs += __shfl_xor(hs, o); hd += __shfl_xor(hd, o);
      }
      if (ll == 0 && r < M) {
        int ulo = panel * 2, uhi = panel * 2 + 1;
        as_out[(size_t)ulo * M + r] = ls;  ad_out[(size_t)ulo * M + r] = ld;
        as_out[(size_t)uhi * M + r] = hs;  ad_out[(size_t)uhi * M + r] = hd;
      }
    }
  }
}

// bf16-quad load helper: uint2 -> 4 floats
__device__ __forceinline__ void bf4(uint2 v, float& f0, float& f1, float& f2, float& f3) {
  f0 = __uint_as_float(v.x << 16);
  f1 = __uint_as_float(v.x & 0xffff0000u);
  f2 = __uint_as_float(v.y << 16);
  f3 = __uint_as_float(v.y & 0xffff0000u);
}

// ---------------- layer 1: block per node, 5 waves (wave = head), LDS reduce ----------------
// Gather: bf16 rows, 16 edges in flight, WAVE-UNIFORM group guards (deg is
// uniform -> scalar branch skips whole 4-edge groups past deg; all lanes
// participate inside taken branches, so the inactive-source ds_bpermute
// hazard (R3-R5 bug) cannot occur). h1 written bf16 for layer-2 MFMA.
__global__ __launch_bounds__(320) void agg1_k(const int* __restrict__ offs,
                                              const int* __restrict__ ssrc,
                                              const float* __restrict__ a_s,
                                              const float* __restrict__ a_d,
                                              const uint2* __restrict__ xwb,
                                              const float* __restrict__ b1,
                                              unsigned short* __restrict__ h1b) {
  int n = blockIdx.x;
  int u = threadIdx.x >> 6;
  int lane = threadIdx.x & 63;
  int off = offs[n], end = offs[n + 1];
  int deg = end - off;
  float ad = a_d[(size_t)u * N_NODES + n];
  const float* asl = a_s + (size_t)u * N_NODES;
  const uint2* xb  = xwb + (size_t)u * N_NODES * 16;
  int g = lane >> 4, q = lane & 15;
  float ax = 0.f, ay = 0.f, az = 0.f, aw = 0.f;

  if (deg <= 64) {
    int s = 0;
    float e = -1e30f;
    if (lane < deg) { s = ssrc[off + lane]; e = lrelu(asl[s] + ad); }
    float m = e;
#pragma unroll
    for (int o = 32; o > 0; o >>= 1) m = fmaxf(m, __shfl_xor(m, o));
    float p = (lane < deg) ? __expf(e - m) : 0.f;
    float den = p;
#pragma unroll
    for (int o = 32; o > 0; o >>= 1) den += __shfl_xor(den, o);
    float alpha = p * (1.f / (den + 1e-16f));

    for (int base = 0; base < deg; base += 16) {
      float alv[4];
      uint2 v[4];
#pragma unroll
      for (int t = 0; t < 4; t++) {
        int b4 = base + t * 4;
        if (b4 < deg) {                       // wave-uniform guard
          int ee = b4 + g;
          bool ok = ee < deg;
          int es = ok ? ee : 0;               // lane 0 always valid (self-loop)
          float alr = __shfl(alpha, es);      // all lanes of taken branch
          int   sv  = __shfl(s, es);
          alv[t] = ok ? alr : 0.f;
          v[t] = xb[(size_t)sv * 16 + q];
        }
      }
#pragma unroll
      for (int t = 0; t < 4; t++) {
        if (base + t * 4 < deg) {             // same uniform guard
          float f0, f1, f2, f3;
          bf4(v[t], f0, f1, f2, f3);
          ax += alv[t] * f0; ay += alv[t] * f1;
          az += alv[t] * f2; aw += alv[t] * f3;
        }
      }
    }
  } else {
    float m = -1e30f;
    for (int i = off + lane; i < end; i += 64) m = fmaxf(m, lrelu(asl[ssrc[i]] + ad));
#pragma unroll
    for (int o = 32; o > 0; o >>= 1) m = fmaxf(m, __shfl_xor(m, o));
    float den = 0.f;
    for (int i = off + lane; i < end; i += 64) den += __expf(lrelu(asl[ssrc[i]] + ad) - m);
#pragma unroll
    for (int o = 32; o > 0; o >>= 1) den += __shfl_xor(den, o);
    float inv = 1.f / (den + 1e-16f);
    for (int base = off; base < end; base += 4) {
      int e = base + g;
      if (e < end) {
        int sv = ssrc[e];
        float al = __expf(lrelu(asl[sv] + ad) - m) * inv;
        float f0, f1, f2, f3;
        bf4(xb[(size_t)sv * 16 + q], f0, f1, f2, f3);
        ax += al * f0; ay += al * f1; az += al * f2; aw += al * f3;
      }
    }
  }

#pragma unroll
  for (int o = 16; o < 64; o <<= 1) {
    ax += __shfl_xor(ax, o); ay += __shfl_xor(ay, o);
    az += __shfl_xor(az, o); aw += __shfl_xor(aw, o);
  }

  __shared__ float sacc[HEADS][64];
  if (g == 0) *(float4*)&sacc[u][q * 4] = make_float4(ax, ay, az, aw);
  __syncthreads();
  if (threadIdx.x < 64) {
    int t = threadIdx.x;
    float v = sacc[0][t] + sacc[1][t] + sacc[2][t] + sacc[3][t] + sacc[4][t];
    v = fmaxf(v * 0.2f + b1[t], 0.f);
    h1b[(size_t)n * 64 + t] = (unsigned short)f2bf(v);
  }
}

// ---------------- layers 2+3: block per node, 5 waves (wave = pair 2g,2g+1) ----------------
__global__ __launch_bounds__(320) void agg23_k(const int* __restrict__ offs,
                                               const int* __restrict__ ssrc,
                                               const float* __restrict__ a_s,
                                               const float* __restrict__ a_d,
                                               const uint2* __restrict__ xwb,
                                               const float* __restrict__ b2,
                                               const float* __restrict__ b3,
                                               float* __restrict__ z_out,
                                               float* __restrict__ mu_out,
                                               float* __restrict__ lv_out) {
  int n = blockIdx.x;
  int gp = threadIdx.x >> 6;
  int lane = threadIdx.x & 63;
  int ulo = 2 * gp, uhi = 2 * gp + 1;
  int off = offs[n], end = offs[n + 1];
  int deg = end - off;
  float adlo = a_d[(size_t)ulo * N_NODES + n];
  float adhi = a_d[(size_t)uhi * N_NODES + n];
  const float* aslo = a_s + (size_t)ulo * N_NODES;
  const float* ashi = a_s + (size_t)uhi * N_NODES;
  const uint2* xb   = xwb + (size_t)gp * N_NODES * 16;
  int g = lane >> 4, q = lane & 15;
  float ax = 0.f, ay = 0.f, az = 0.f, aw = 0.f;

  if (deg <= 64) {
    int s = 0;
    float elo = -1e30f, ehi = -1e30f;
    if (lane < deg) {
      s = ssrc[off + lane];
      elo = lrelu(aslo[s] + adlo);
      ehi = lrelu(ashi[s] + adhi);
    }
    float mlo = elo, mhi = ehi;
#pragma unroll
    for (int o = 32; o > 0; o >>= 1) {
      mlo = fmaxf(mlo, __shfl_xor(mlo, o));
      mhi = fmaxf(mhi, __shfl_xor(mhi, o));
    }
    float plo = (lane < deg) ? __expf(elo - mlo) : 0.f;
    float phi = (lane < deg) ? __expf(ehi - mhi) : 0.f;
    float dlo = plo, dhi = phi;
#pragma unroll
    for (int o = 32; o > 0; o >>= 1) {
      dlo += __shfl_xor(dlo, o);
      dhi += __shfl_xor(dhi, o);
    }
    float allo = plo * (1.f / (dlo + 1e-16f));
    float alhi = phi * (1.f / (dhi + 1e-16f));

    for (int base = 0; base < deg; base += 16) {
      float alv[4];
      uint2 v[4];
#pragma unroll
      for (int t = 0; t < 4; t++) {
        int b4 = base + t * 4;
        if (b4 < deg) {                       // wave-uniform guard
          int ee = b4 + g;
          bool ok = ee < deg;
          int es = ok ? ee : 0;
          float a1 = __shfl(allo, es);        // all lanes of taken branch
          float a2 = __shfl(alhi, es);
          int   sv = __shfl(s, es);
          float alr = (q < 8) ? a1 : a2;
          alv[t] = ok ? alr : 0.f;
          v[t] = xb[(size_t)sv * 16 + q];
        }
      }
#pragma unroll
      for (int t = 0; t < 4; t++) {
        if (base + t * 4 < deg) {             // same uniform guard
          float f0, f1, f2, f3;
          bf4(v[t], f0, f1, f2, f3);
          ax += alv[t] * f0; ay += alv[t] * f1;
          az += alv[t] * f2; aw += alv[t] * f3;
        }
      }
    }
  } else {
    float mlo = -1e30f, mhi = -1e30f;
    for (int i = off + lane; i < end; i += 64) {
      int sv = ssrc[i];
      mlo = fmaxf(mlo, lrelu(aslo[sv] + adlo));
      mhi = fmaxf(mhi, lrelu(ashi[sv] + adhi));
    }
#pragma unroll
    for (int o = 32; o > 0; o >>= 1) {
      mlo = fmaxf(mlo, __shfl_xor(mlo, o));
      mhi = fmaxf(mhi, __shfl_xor(mhi, o));
    }
    float dlo = 0.f, dhi = 0.f;
    for (int i = off + lane; i < end; i += 64) {
      int sv = ssrc[i];
      dlo += __expf(lrelu(aslo[sv] + adlo) - mlo);
      dhi += __expf(lrelu(ashi[sv] + adhi) - mhi);
    }
#pragma unroll
    for (int o = 32; o > 0; o >>= 1) {
      dlo += __shfl_xor(dlo, o);
      dhi += __shfl_xor(dhi, o);
    }
    float ilo = 1.f / (dlo + 1e-16f), ihi = 1.f / (dhi + 1e-16f);
    for (int base = off; base < end; base += 4) {
      int e = base + g;
      if (e < end) {
        int sv = ssrc[e];
        float al;
        if (q < 8) al = __expf(lrelu(aslo[sv] + adlo) - mlo) * ilo;
        else       al = __expf(lrelu(ashi[sv] + adhi) - mhi) * ihi;
        float f0, f1, f2, f3;
        bf4(xb[(size_t)sv * 16 + q], f0, f1, f2, f3);
        ax += al * f0; ay += al * f1; az += al * f2; aw += al * f3;
      }
    }
  }

#pragma unroll
  for (int o = 16; o < 64; o <<= 1) {
    ax += __shfl_xor(ax, o); ay += __shfl_xor(ay, o);
    az += __shfl_xor(az, o); aw += __shfl_xor(aw, o);
  }

  __shared__ float sacc[HEADS][2][32];
  if (g == 0)
    *(float4*)&sacc[gp][q >> 3][(q & 7) * 4] = make_float4(ax, ay, az, aw);
  __syncthreads();
  if (threadIdx.x < 64) {
    int t = threadIdx.x;
    if (t < 32) {
      float v = sacc[0][0][t] + sacc[0][1][t] + sacc[1][0][t] + sacc[1][1][t] + sacc[2][0][t];
      v = v * 0.2f + b2[t];
      z_out[(size_t)n * 32 + t]  = v;
      mu_out[(size_t)n * 32 + t] = v;
    } else {
      int c = t - 32;
      float v = sacc[2][1][c] + sacc[3][0][c] + sacc[3][1][c] + sacc[4][0][c] + sacc[4][1][c];
      v = v * 0.2f + b3[c];
      lv_out[(size_t)n * 32 + c] = v;
    }
  }
}

// ---------------- launch ----------------
extern "C" void kernel_launch(void* const* d_in, const int* in_sizes, int n_in,
                              void* d_out, int out_size, void* d_ws, size_t ws_size,
                              hipStream_t stream) {
  const float* x        = (const float*)d_in[0];
  const int*   ei       = (const int*)d_in[1];
  const float* W1       = (const float*)d_in[2];
  const float* att_src1 = (const float*)d_in[3];
  const float* att_dst1 = (const float*)d_in[4];
  const float* b1       = (const float*)d_in[5];
  const float* W2       = (const float*)d_in[6];
  const float* att_src2 = (const float*)d_in[7];
  const float* att_dst2 = (const float*)d_in[8];
  const float* b2       = (const float*)d_in[9];
  const float* W3       = (const float*)d_in[10];
  const float* att_src3 = (const float*)d_in[11];
  const float* att_dst3 = (const float*)d_in[12];
  const float* b3       = (const float*)d_in[13];
  float* out = (float*)d_out;

  char* w = (char*)d_ws;
  auto alloc = [&](size_t bytes) -> void* {
    void* p = (void*)w;
    w += (bytes + 255) & ~(size_t)255;
    return p;
  };
  int*            deg    = (int*)alloc((size_t)N_NODES * 4);
  int*            offs   = (int*)alloc((size_t)(N_NODES + 1) * 4);
  int*            cursor = (int*)alloc((size_t)N_NODES * 4);
  int*            bsum   = (int*)alloc((size_t)128 * 4);
  int*            ssrc   = (int*)alloc((size_t)EP * 4);
  unsigned short* xwb    = (unsigned short*)alloc((size_t)N_NODES * 320 * 2);  // 12.8 MB
  float*          a_s    = (float*)alloc((size_t)N_NODES * 10 * 4);
  float*          a_d    = (float*)alloc((size_t)N_NODES * 10 * 4);
  unsigned short* h1b    = (unsigned short*)alloc((size_t)N_NODES * 64 * 2);   // 2.56 MB
  unsigned short* xbf    = (unsigned short*)alloc((size_t)N_NODES * 256 * 2);  // 10.24 MB
  unsigned short* Wp1    = (unsigned short*)alloc((size_t)256 * 320 * 2);
  unsigned short* Wp23   = (unsigned short*)alloc((size_t)64 * 320 * 2);
  // total ~29 MB (< proven ~34 MB)

  hipMemsetAsync(deg, 0, (size_t)N_NODES * 4, stream);
  hipMemsetAsync(cursor, 0, (size_t)N_NODES * 4, stream);

  int eb = (EP + 255) / 256;
  int nb = (N_NODES + 255) / 256;   // 79
  count_deg_k<<<eb, 256, 0, stream>>>(ei, deg);
  scan1_k<<<nb, 256, 0, stream>>>(deg, offs, bsum);
  scan2_k<<<1, 128, 0, stream>>>(bsum, nb);
  scan3_k<<<nb, 256, 0, stream>>>(offs, bsum);
  scatter_k<<<eb, 256, 0, stream>>>(ei, offs, cursor, ssrc);

  int nx4 = N_NODES * 256 / 4;
  conv_bf16_k<<<(nx4 + 255) / 256, 256, 0, stream>>>((const float4*)x, (uint2*)xbf, nx4);
  packW1_k<<<(256 * 320 + 255) / 256, 256, 0, stream>>>(W1, Wp1);
  packW23_k<<<(64 * 320 + 255) / 256, 256, 0, stream>>>(W2, W3, Wp23);

  dim3 gg(5, 313);   // panel-fast: 5 panels of one A row-tile are consecutive

  // ---- layer 1 ----
  mfma_gemm_k<8, 64><<<gg, 256, 0, stream>>>(xbf, Wp1, xwb,
                                             att_src1, att_dst1, nullptr, nullptr,
                                             a_s, a_d, N_NODES);
  agg1_k<<<N_NODES, 320, 0, stream>>>(offs, ssrc, a_s, a_d, (const uint2*)xwb, b1, h1b);

  // ---- layers 2+3 fused ----
  mfma_gemm_k<2, 32><<<gg, 256, 0, stream>>>(h1b, Wp23, xwb,
                                             att_src2, att_dst2, att_src3, att_dst3,
                                             a_s, a_d, N_NODES);
  agg23_k<<<N_NODES, 320, 0, stream>>>(offs, ssrc, a_s, a_d, (const uint2*)xwb, b2, b3,
                                       out, out + (size_t)N_NODES * 32,
                                       out + (size_t)2 * N_NODES * 32);
}